// Round 9
// baseline (219.466 us; speedup 1.0000x reference)
//
#include <hip/hip_runtime.h>
#include <math.h>

#define N_NODES 200000
#define N_VAR   112000
#define N_EDGES 3200000
#define NB_SCAN 782           // ceil(200000/256)
#define CAP     64            // padded row capacity (P(deg>=64)~1e-24); == wave size

// ---- two-level counting-sort params ----
#define NFINE    512          // fine dst-range buckets
#define PSZ_F    391          // nodes per bucket (512*391 = 200192 >= 200000)
#define FCAP     7168         // per-bucket edge capacity (mean 6250, ~11.6 sigma slack)
#define BIN_CHUNK 8192        // edges per k_bin block (391 blocks; measured best)
#define NB_BIN   391          // ceil(3.2e6/8192)

typedef int v4i __attribute__((ext_vector_type(4)));

// broadcast lane j's value to all lanes via the LDS-pipe crossbar
// (ds_bpermute: no LDS storage, no bank conflicts, frees VALU issue slots).
// All call sites run with full exec (n is wave-uniform), so semantics are safe.
__device__ __forceinline__ float bcast_lane(float x, int lane) {
    return __int_as_float(__builtin_amdgcn_ds_bpermute(lane << 2, __float_as_int(x)));
}

// ---------- phase A: bin edges into 512 dst-range buckets + folded setup ----------
// Packed entry: (dst_local<<18 | src), dst_local<391 (9b), src<2^18.
// 8192-edge chunks + wave-shuffle scan (2 barriers) + fused Wc/bc fold.
__global__ void __launch_bounds__(512) k_bin(const int* __restrict__ src,
                                             const int* __restrict__ dst,
                                             int* __restrict__ bins,
                                             int* __restrict__ bcnt,
                                             const float* __restrict__ W2,
                                             const float* __restrict__ b2,
                                             const float* __restrict__ Wfc,
                                             const float* __restrict__ bfc,
                                             float* __restrict__ Wc,
                                             float* __restrict__ bc) {
    __shared__ int hist[NFINE];
    __shared__ int seg[NFINE];
    __shared__ int gb[NFINE];
    __shared__ int cur[NFINE];
    __shared__ int wsum[8];
    __shared__ int stg[BIN_CHUNK];
    __shared__ unsigned short stgb[BIN_CHUNK];
    int tid = threadIdx.x;
    int lane = tid & 63, wid = tid >> 6;
    hist[tid] = 0;
    __syncthreads();

    int base = blockIdx.x * BIN_CHUNK;
    int pk[4][4];
    int bk[4][4];
    bool val[4];
    #pragma unroll
    for (int i = 0; i < 4; ++i) {
        int e4 = base + (i * 512 + tid) * 4;
        val[i] = (e4 < N_EDGES);       // N_EDGES % 4 == 0 -> full quad if valid
        if (val[i]) {
            v4i d = __builtin_nontemporal_load((const v4i*)(dst + e4));
            v4i s = __builtin_nontemporal_load((const v4i*)(src + e4));
            int dd[4] = {d.x, d.y, d.z, d.w};
            int ss[4] = {s.x, s.y, s.z, s.w};
            #pragma unroll
            for (int q = 0; q < 4; ++q) {
                int bb2 = dd[q] / PSZ_F;               // const div -> magic mul
                int dl = dd[q] - bb2 * PSZ_F;          // < 391 (9 bits)
                pk[i][q] = (dl << 18) | ss[q];
                bk[i][q] = bb2;
                atomicAdd(&hist[bb2], 1);
            }
        }
    }
    __syncthreads();

    // wave-shuffle inclusive scan over 512 entries (2 barriers total)
    int h = hist[tid];
    int inc = h;
    #pragma unroll
    for (int d = 1; d < 64; d <<= 1) {
        int t = __shfl_up(inc, d);
        if (lane >= d) inc += t;
    }
    if (lane == 63) wsum[wid] = inc;
    __syncthreads();
    int pre = 0, tot = 0;
    #pragma unroll
    for (int k = 0; k < 8; ++k) {
        int s = wsum[k];
        pre += (k < wid) ? s : 0;
        tot += s;
    }
    int ex = pre + inc - h;
    seg[tid] = ex;
    cur[tid] = ex;
    gb[tid]  = atomicAdd(&bcnt[tid], h);
    __syncthreads();

    // compact into stg by bucket
    #pragma unroll
    for (int i = 0; i < 4; ++i) {
        if (val[i]) {
            #pragma unroll
            for (int q = 0; q < 4; ++q) {
                int p = atomicAdd(&cur[bk[i][q]], 1);
                stg[p]  = pk[i][q];
                stgb[p] = (unsigned short)bk[i][q];
            }
        }
    }
    __syncthreads();

    // coalesced copy-out: per-bucket contiguous runs (avg 16 edges = 64B)
    for (int i = tid; i < tot; i += 512) {
        int bb2 = stgb[i];
        int pos = gb[bb2] + (i - seg[bb2]);
        if (pos < FCAP)
            bins[(size_t)bb2 * FCAP + pos] = stg[i];
    }

    // folded setup (identical f64 math to original k_setup)
    int b = blockIdx.x;
    if (b < 8) {
        int e = b * 512 + tid;             // 4096 entries
        int j = e >> 6, l2 = e & 63;
        double acc = 0.0;
        for (int m = 0; m < 64; ++m)
            acc += (double)W2[j * 64 + m] * (double)Wfc[m * 64 + l2];
        Wc[e] = (float)acc;
    } else if (b == 8 && tid < 64) {
        double acc = (double)bfc[tid];
        for (int m = 0; m < 64; ++m)
            acc += (double)b2[m] * (double)Wfc[m * 64 + tid];
        bc[tid] = (float)acc;
    }
}

// ---------- phase B: per-bucket counting sort -> exact cnt + xdc + coalesced buf ----------
__global__ void __launch_bounds__(512) k_sort(const int* __restrict__ bins,
                                              const int* __restrict__ bcnt,
                                              const float2* __restrict__ x2,
                                              int* __restrict__ cnt,
                                              float4* __restrict__ xdc,
                                              int* __restrict__ buf) {
    __shared__ int hist[NFINE];
    __shared__ int off[NFINE];
    __shared__ int cur[NFINE];
    __shared__ int wsum[8];
    __shared__ int sorted[FCAP];
    __shared__ unsigned short rowid[FCAP];
    int tid = threadIdx.x;
    int lane = tid & 63, wid = tid >> 6;
    int b = blockIdx.x;
    int n = bcnt[b];
    if (n > FCAP) n = FCAP;
    const int* __restrict__ bp = bins + (size_t)b * FCAP;

    hist[tid] = 0;
    __syncthreads();
    for (int i = tid; i < n; i += 512)
        atomicAdd(&hist[bp[i] >> 18], 1);
    __syncthreads();

    int h = hist[tid];

    // exact degree -> cnt + xdc (fused k_post; same math)
    int vg = b * PSZ_F + tid;
    if (tid < PSZ_F && vg < N_NODES) {
        cnt[vg] = h;
        float dvv = rsqrtf((float)h + 1.0f);
        float2 xv = x2[vg];
        xdc[vg] = make_float4(xv.x * dvv, xv.y * dvv, dvv, 0.0f);
    }

    // wave-shuffle inclusive scan -> exclusive offsets
    int inc = h;
    #pragma unroll
    for (int d = 1; d < 64; d <<= 1) {
        int t = __shfl_up(inc, d);
        if (lane >= d) inc += t;
    }
    if (lane == 63) wsum[wid] = inc;
    __syncthreads();
    int pre = 0;
    #pragma unroll
    for (int k = 0; k < 8; ++k) {
        int s = wsum[k];
        pre += (k < wid) ? s : 0;
    }
    int ex = pre + inc - h;
    off[tid] = ex;
    cur[tid] = ex;
    __syncthreads();

    // LDS reorder: dst-sorted edge list
    for (int i = tid; i < n; i += 512) {
        int pkv = bp[i];
        int dl = pkv >> 18;
        int p = atomicAdd(&cur[dl], 1);
        sorted[p] = pkv & 0x3FFFF;
        rowid[p]  = (unsigned short)dl;
    }
    __syncthreads();

    // monotone coalesced write-out of padded rows
    for (int i = tid; i < n; i += 512) {
        int dl = rowid[i];
        int slot = i - off[dl];
        if (slot < CAP)
            buf[(size_t)(b * PSZ_F + dl) * CAP + slot] = sorted[i];
    }
}

// ---------- layer 1: zn[v] = (i0, i1, dv, 0) -- f32 partial accumulators ----------
__global__ void __launch_bounds__(256) k_l1a(const int* __restrict__ cnt,
                                             const int* __restrict__ buf,
                                             const float4* __restrict__ xdc,
                                             float4* __restrict__ zn) {
    int v = blockIdx.x * 256 + threadIdx.x;
    if (v >= N_NODES) return;
    int c = cnt[v];
    int n = (c < CAP) ? c : CAP;
    const int* __restrict__ rowp = buf + v * CAP;
    float4 self = xdc[v];
    float dv = self.z;
    float ax = self.x, ay = self.y;
    float bx = 0.0f,   by = 0.0f;
    int j = 0;
    for (; j + 16 <= n; j += 16) {
        v4i r0 = __builtin_nontemporal_load((const v4i*)(rowp + j));
        v4i r1 = __builtin_nontemporal_load((const v4i*)(rowp + j + 4));
        v4i r2 = __builtin_nontemporal_load((const v4i*)(rowp + j + 8));
        v4i r3 = __builtin_nontemporal_load((const v4i*)(rowp + j + 12));
        float4 p0 = xdc[r0.x], p1 = xdc[r0.y], p2 = xdc[r0.z], p3 = xdc[r0.w];
        float4 p4 = xdc[r1.x], p5 = xdc[r1.y], p6 = xdc[r1.z], p7 = xdc[r1.w];
        float4 p8 = xdc[r2.x], p9 = xdc[r2.y], pa = xdc[r2.z], pb = xdc[r2.w];
        float4 pc = xdc[r3.x], pd = xdc[r3.y], pe = xdc[r3.z], pf = xdc[r3.w];
        ax += p0.x; ay += p0.y;  bx += p1.x; by += p1.y;
        ax += p2.x; ay += p2.y;  bx += p3.x; by += p3.y;
        ax += p4.x; ay += p4.y;  bx += p5.x; by += p5.y;
        ax += p6.x; ay += p6.y;  bx += p7.x; by += p7.y;
        ax += p8.x; ay += p8.y;  bx += p9.x; by += p9.y;
        ax += pa.x; ay += pa.y;  bx += pb.x; by += pb.y;
        ax += pc.x; ay += pc.y;  bx += pd.x; by += pd.y;
        ax += pe.x; ay += pe.y;  bx += pf.x; by += pf.y;
    }
    for (; j + 8 <= n; j += 8) {
        v4i r0 = __builtin_nontemporal_load((const v4i*)(rowp + j));
        v4i r1 = __builtin_nontemporal_load((const v4i*)(rowp + j + 4));
        float4 p0 = xdc[r0.x], p1 = xdc[r0.y], p2 = xdc[r0.z], p3 = xdc[r0.w];
        float4 p4 = xdc[r1.x], p5 = xdc[r1.y], p6 = xdc[r1.z], p7 = xdc[r1.w];
        ax += p0.x; ay += p0.y;  bx += p1.x; by += p1.y;
        ax += p2.x; ay += p2.y;  bx += p3.x; by += p3.y;
        ax += p4.x; ay += p4.y;  bx += p5.x; by += p5.y;
        ax += p6.x; ay += p6.y;  bx += p7.x; by += p7.y;
    }
    for (; j < n; ++j) {
        int s = rowp[j];
        float4 p = xdc[s];
        ax += p.x; ay += p.y;
    }
    zn[v] = make_float4((ax + bx) * dv, (ay + by) * dv, dv, 0.0f);
}

// ---------- layer 2 + folded fc, var nodes only -- all-f32, zero LDS storage ----------
// R8 structure (measured 65us, VGPR 52) with ONE change: all lane-broadcasts
// go through ds_bpermute (LDS-pipe crossbar) instead of v_readlane (VALU).
// ~37% of the per-node issue slots move off the saturated VALU pipe onto the
// idle LDS pipe; with ~3 waves/SIMD the pipes co-issue. Pure data movement --
// FP op order bit-identical to R8.
__global__ void __launch_bounds__(256, 4) k_l2(const int* __restrict__ cnt,
                                               const int* __restrict__ buf,
                                               const float4* __restrict__ zn,
                                               const float* __restrict__ W1,
                                               const float* __restrict__ b1,
                                               const float* __restrict__ Wc,
                                               const float* __restrict__ bc,
                                               float* __restrict__ out) {
    int w = threadIdx.x >> 6, l = threadIdx.x & 63;
    float wc[64];
    #pragma unroll
    for (int jv = 0; jv < 64; ++jv)
        wc[jv] = Wc[jv * 64 + l];
    float w1a = W1[l], w1b = W1[64 + l], bb = b1[l];
    float bcl = bc[l];
    int v0 = blockIdx.x * 16 + w;          // wave w owns v0, v0+4, v0+8, v0+12
    int cc0 = __builtin_amdgcn_readfirstlane(cnt[v0]);
    int cc1 = __builtin_amdgcn_readfirstlane(cnt[v0 + 4]);
    int cc2 = __builtin_amdgcn_readfirstlane(cnt[v0 + 8]);
    int cc3 = __builtin_amdgcn_readfirstlane(cnt[v0 + 12]);

    // hoisted loads: rows + neighbor gathers + selfs, all in flight up front
    int nn[4];
    float4 p[4], zs[4];
    #pragma unroll
    for (int it = 0; it < 4; ++it) {
        int v = v0 + it * 4;
        int c = (it == 0) ? cc0 : (it == 1) ? cc1 : (it == 2) ? cc2 : cc3;
        int n = (c < CAP) ? c : CAP;
        nn[it] = n;
        int ridx = __builtin_nontemporal_load(buf + v * CAP + l);
        int idx  = (l < n) ? ridx : v;
        p[it]  = zn[idx];                  // per-lane gather: lane i = neighbor i
        zs[it] = zn[v];                    // self (uniform)
    }

    #pragma unroll
    for (int it = 0; it < 4; ++it) {
        int v = v0 + it * 4;
        int c = (it == 0) ? cc0 : (it == 1) ? cc1 : (it == 2) ? cc2 : cc3;
        int n = nn[it];
        float dv = rsqrtf((float)c + 1.0f);
        float4 pp = p[it];
        float4 zss = zs[it];

        float acc0 = fmaxf(fmaf(zss.x, w1a, fmaf(zss.y, w1b, bb)), 0.0f) * zss.z;
        float acc1 = 0.0f;
        int j = 0;
        for (; j + 8 <= n; j += 8) {
            float x0 = bcast_lane(pp.x, j+0), y0 = bcast_lane(pp.y, j+0), z0 = bcast_lane(pp.z, j+0);
            float x1 = bcast_lane(pp.x, j+1), y1 = bcast_lane(pp.y, j+1), z1 = bcast_lane(pp.z, j+1);
            float x2 = bcast_lane(pp.x, j+2), y2 = bcast_lane(pp.y, j+2), z2 = bcast_lane(pp.z, j+2);
            float x3 = bcast_lane(pp.x, j+3), y3 = bcast_lane(pp.y, j+3), z3 = bcast_lane(pp.z, j+3);
            float x4 = bcast_lane(pp.x, j+4), y4 = bcast_lane(pp.y, j+4), z4 = bcast_lane(pp.z, j+4);
            float x5 = bcast_lane(pp.x, j+5), y5 = bcast_lane(pp.y, j+5), z5 = bcast_lane(pp.z, j+5);
            float x6 = bcast_lane(pp.x, j+6), y6 = bcast_lane(pp.y, j+6), z6 = bcast_lane(pp.z, j+6);
            float x7 = bcast_lane(pp.x, j+7), y7 = bcast_lane(pp.y, j+7), z7 = bcast_lane(pp.z, j+7);
            float h0 = fmaxf(fmaf(x0, w1a, fmaf(y0, w1b, bb)), 0.0f) * z0;
            float h1 = fmaxf(fmaf(x1, w1a, fmaf(y1, w1b, bb)), 0.0f) * z1;
            float h2 = fmaxf(fmaf(x2, w1a, fmaf(y2, w1b, bb)), 0.0f) * z2;
            float h3 = fmaxf(fmaf(x3, w1a, fmaf(y3, w1b, bb)), 0.0f) * z3;
            float h4 = fmaxf(fmaf(x4, w1a, fmaf(y4, w1b, bb)), 0.0f) * z4;
            float h5 = fmaxf(fmaf(x5, w1a, fmaf(y5, w1b, bb)), 0.0f) * z5;
            float h6 = fmaxf(fmaf(x6, w1a, fmaf(y6, w1b, bb)), 0.0f) * z6;
            float h7 = fmaxf(fmaf(x7, w1a, fmaf(y7, w1b, bb)), 0.0f) * z7;
            acc0 += (h0 + h1) + (h2 + h3);
            acc1 += (h4 + h5) + (h6 + h7);
        }
        for (; j + 4 <= n; j += 4) {
            float x0 = bcast_lane(pp.x, j+0), y0 = bcast_lane(pp.y, j+0), z0 = bcast_lane(pp.z, j+0);
            float x1 = bcast_lane(pp.x, j+1), y1 = bcast_lane(pp.y, j+1), z1 = bcast_lane(pp.z, j+1);
            float x2 = bcast_lane(pp.x, j+2), y2 = bcast_lane(pp.y, j+2), z2 = bcast_lane(pp.z, j+2);
            float x3 = bcast_lane(pp.x, j+3), y3 = bcast_lane(pp.y, j+3), z3 = bcast_lane(pp.z, j+3);
            float h0 = fmaxf(fmaf(x0, w1a, fmaf(y0, w1b, bb)), 0.0f) * z0;
            float h1 = fmaxf(fmaf(x1, w1a, fmaf(y1, w1b, bb)), 0.0f) * z1;
            float h2 = fmaxf(fmaf(x2, w1a, fmaf(y2, w1b, bb)), 0.0f) * z2;
            float h3 = fmaxf(fmaf(x3, w1a, fmaf(y3, w1b, bb)), 0.0f) * z3;
            acc0 += (h0 + h1) + (h2 + h3);
        }
        for (; j < n; ++j) {
            float xk = bcast_lane(pp.x, j), yk = bcast_lane(pp.y, j), zk = bcast_lane(pp.z, j);
            acc1 += fmaxf(fmaf(xk, w1a, fmaf(yk, w1b, bb)), 0.0f) * zk;
        }
        float Av = (acc0 + acc1) * dv;     // lane l holds channel l's aggregate

        // FC: identical accumulation grouping to R3-R8 -> same FP result.
        float t0 = 0.0f, t1 = 0.0f, t2 = 0.0f, t3 = 0.0f;
        #pragma unroll
        for (int jj = 0; jj < 64; jj += 4) {
            t0 = fmaf(bcast_lane(Av, jj + 0), wc[jj + 0], t0);
            t1 = fmaf(bcast_lane(Av, jj + 1), wc[jj + 1], t1);
            t2 = fmaf(bcast_lane(Av, jj + 2), wc[jj + 2], t2);
            t3 = fmaf(bcast_lane(Av, jj + 3), wc[jj + 3], t3);
        }
        float t = ((t0 + t1) + (t2 + t3)) + bcl;
        __builtin_nontemporal_store(rintf(fmaxf(t, 0.0f)), out + v * 64 + l);
    }
}

// ---------------- launch ----------------

extern "C" void kernel_launch(void* const* d_in, const int* in_sizes, int n_in,
                              void* d_out, int out_size, void* d_ws, size_t ws_size,
                              hipStream_t stream) {
    const float* x    = (const float*)d_in[0];
    const int*   ei   = (const int*)  d_in[1];
    const float* W1   = (const float*)d_in[2];
    const float* b1   = (const float*)d_in[3];
    const float* W2   = (const float*)d_in[4];
    const float* b2   = (const float*)d_in[5];
    const float* Wfc  = (const float*)d_in[6];
    const float* bfc  = (const float*)d_in[7];
    float* out = (float*)d_out;

    const int* src = ei;
    const int* dst = ei + N_EDGES;

    // workspace layout (bytes), 16-aligned; total 70,420,736 (unchanged size)
    //   cnt  [0, 800000)            written k_sort, read l1a/l2
    //   xdc  [800000, 4000000)      written k_sort, read l1a       (no alias)
    //   bins [4000000, 18680064)    written k_bin, read k_sort
    //   bcnt [18680064, 18682112)   memset, k_bin atomics, k_sort read
    //   zn   [15204096, 18404096)   written l1a (bins dead), read l2
    //   buf  [19204096, 70404096)   written k_sort, read l1a/l2
    //   Wc/bc[70404096, 70420736)   written k_bin blocks 0..8, read l2
    char* ws = (char*)d_ws;
    int*    cnt    = (int*)   (ws + 0);
    float4* xdc    = (float4*)(ws + 800000);
    int*    bins   = (int*)   (ws + 4000000);
    int*    bcnt   = (int*)   (ws + 18680064);
    float4* zn     = (float4*)(ws + 15204096);   // aliases dead bins tail
    int*    buf    = (int*)   (ws + 19204096);
    float*  Wc     = (float*) (ws + 70404096);
    float*  bc     = (float*) (ws + 70420480);

    hipMemsetAsync(bcnt, 0, NFINE * sizeof(int), stream);
    k_bin  <<<NB_BIN, 512, 0, stream>>>(src, dst, bins, bcnt, W2, b2, Wfc, bfc, Wc, bc);
    k_sort <<<NFINE, 512, 0, stream>>>(bins, bcnt, (const float2*)x, cnt, xdc, buf);
    k_l1a  <<<NB_SCAN, 256, 0, stream>>>(cnt, buf, xdc, zn);
    k_l2   <<<N_VAR / 16, 256, 0, stream>>>(cnt, buf, zn, W1, b1, Wc, bc, out);
}

// Round 10
// 206.057 us; speedup vs baseline: 1.0651x; 1.0651x over previous
//
#include <hip/hip_runtime.h>
#include <math.h>

#define N_NODES 200000
#define N_VAR   112000
#define N_EDGES 3200000
#define NB_SCAN 782           // ceil(200000/256)
#define CAP     64            // padded row capacity (P(deg>=64)~1e-24); == wave size

// ---- two-level counting-sort params ----
#define NFINE    512          // fine dst-range buckets
#define PSZ_F    391          // nodes per bucket (512*391 = 200192 >= 200000)
#define FCAP     7168         // per-bucket edge capacity (mean 6250, ~11.6 sigma slack)
#define BIN_CHUNK 8192        // edges per k_bin block (391 blocks; measured best)
#define NB_BIN   391          // ceil(3.2e6/8192)

typedef int v4i __attribute__((ext_vector_type(4)));

// ---------- phase A: bin edges into 512 dst-range buckets + folded setup ----------
// Packed entry: (dst_local<<18 | src), dst_local<391 (9b), src<2^18.
// 8192-edge chunks + wave-shuffle scan (2 barriers) + fused Wc/bc fold.
__global__ void __launch_bounds__(512) k_bin(const int* __restrict__ src,
                                             const int* __restrict__ dst,
                                             int* __restrict__ bins,
                                             int* __restrict__ bcnt,
                                             const float* __restrict__ W2,
                                             const float* __restrict__ b2,
                                             const float* __restrict__ Wfc,
                                             const float* __restrict__ bfc,
                                             float* __restrict__ Wc,
                                             float* __restrict__ bc) {
    __shared__ int hist[NFINE];
    __shared__ int seg[NFINE];
    __shared__ int gb[NFINE];
    __shared__ int cur[NFINE];
    __shared__ int wsum[8];
    __shared__ int stg[BIN_CHUNK];
    __shared__ unsigned short stgb[BIN_CHUNK];
    int tid = threadIdx.x;
    int lane = tid & 63, wid = tid >> 6;
    hist[tid] = 0;
    __syncthreads();

    int base = blockIdx.x * BIN_CHUNK;
    int pk[4][4];
    int bk[4][4];
    bool val[4];
    #pragma unroll
    for (int i = 0; i < 4; ++i) {
        int e4 = base + (i * 512 + tid) * 4;
        val[i] = (e4 < N_EDGES);       // N_EDGES % 4 == 0 -> full quad if valid
        if (val[i]) {
            v4i d = __builtin_nontemporal_load((const v4i*)(dst + e4));
            v4i s = __builtin_nontemporal_load((const v4i*)(src + e4));
            int dd[4] = {d.x, d.y, d.z, d.w};
            int ss[4] = {s.x, s.y, s.z, s.w};
            #pragma unroll
            for (int q = 0; q < 4; ++q) {
                int bb2 = dd[q] / PSZ_F;               // const div -> magic mul
                int dl = dd[q] - bb2 * PSZ_F;          // < 391 (9 bits)
                pk[i][q] = (dl << 18) | ss[q];
                bk[i][q] = bb2;
                atomicAdd(&hist[bb2], 1);
            }
        }
    }
    __syncthreads();

    // wave-shuffle inclusive scan over 512 entries (2 barriers total)
    int h = hist[tid];
    int inc = h;
    #pragma unroll
    for (int d = 1; d < 64; d <<= 1) {
        int t = __shfl_up(inc, d);
        if (lane >= d) inc += t;
    }
    if (lane == 63) wsum[wid] = inc;
    __syncthreads();
    int pre = 0, tot = 0;
    #pragma unroll
    for (int k = 0; k < 8; ++k) {
        int s = wsum[k];
        pre += (k < wid) ? s : 0;
        tot += s;
    }
    int ex = pre + inc - h;
    seg[tid] = ex;
    cur[tid] = ex;
    gb[tid]  = atomicAdd(&bcnt[tid], h);
    __syncthreads();

    // compact into stg by bucket
    #pragma unroll
    for (int i = 0; i < 4; ++i) {
        if (val[i]) {
            #pragma unroll
            for (int q = 0; q < 4; ++q) {
                int p = atomicAdd(&cur[bk[i][q]], 1);
                stg[p]  = pk[i][q];
                stgb[p] = (unsigned short)bk[i][q];
            }
        }
    }
    __syncthreads();

    // coalesced copy-out: per-bucket contiguous runs (avg 16 edges = 64B)
    for (int i = tid; i < tot; i += 512) {
        int bb2 = stgb[i];
        int pos = gb[bb2] + (i - seg[bb2]);
        if (pos < FCAP)
            bins[(size_t)bb2 * FCAP + pos] = stg[i];
    }

    // folded setup (identical f64 math to original k_setup)
    int b = blockIdx.x;
    if (b < 8) {
        int e = b * 512 + tid;             // 4096 entries
        int j = e >> 6, l2 = e & 63;
        double acc = 0.0;
        for (int m = 0; m < 64; ++m)
            acc += (double)W2[j * 64 + m] * (double)Wfc[m * 64 + l2];
        Wc[e] = (float)acc;
    } else if (b == 8 && tid < 64) {
        double acc = (double)bfc[tid];
        for (int m = 0; m < 64; ++m)
            acc += (double)b2[m] * (double)Wfc[m * 64 + tid];
        bc[tid] = (float)acc;
    }
}

// ---------- phase B: per-bucket counting sort -> exact cnt + xdc + coalesced buf ----------
__global__ void __launch_bounds__(512) k_sort(const int* __restrict__ bins,
                                              const int* __restrict__ bcnt,
                                              const float2* __restrict__ x2,
                                              int* __restrict__ cnt,
                                              float4* __restrict__ xdc,
                                              int* __restrict__ buf) {
    __shared__ int hist[NFINE];
    __shared__ int off[NFINE];
    __shared__ int cur[NFINE];
    __shared__ int wsum[8];
    __shared__ int sorted[FCAP];
    __shared__ unsigned short rowid[FCAP];
    int tid = threadIdx.x;
    int lane = tid & 63, wid = tid >> 6;
    int b = blockIdx.x;
    int n = bcnt[b];
    if (n > FCAP) n = FCAP;
    const int* __restrict__ bp = bins + (size_t)b * FCAP;

    hist[tid] = 0;
    __syncthreads();
    for (int i = tid; i < n; i += 512)
        atomicAdd(&hist[bp[i] >> 18], 1);
    __syncthreads();

    int h = hist[tid];

    // exact degree -> cnt + xdc (fused k_post; same math)
    int vg = b * PSZ_F + tid;
    if (tid < PSZ_F && vg < N_NODES) {
        cnt[vg] = h;
        float dvv = rsqrtf((float)h + 1.0f);
        float2 xv = x2[vg];
        xdc[vg] = make_float4(xv.x * dvv, xv.y * dvv, dvv, 0.0f);
    }

    // wave-shuffle inclusive scan -> exclusive offsets
    int inc = h;
    #pragma unroll
    for (int d = 1; d < 64; d <<= 1) {
        int t = __shfl_up(inc, d);
        if (lane >= d) inc += t;
    }
    if (lane == 63) wsum[wid] = inc;
    __syncthreads();
    int pre = 0;
    #pragma unroll
    for (int k = 0; k < 8; ++k) {
        int s = wsum[k];
        pre += (k < wid) ? s : 0;
    }
    int ex = pre + inc - h;
    off[tid] = ex;
    cur[tid] = ex;
    __syncthreads();

    // LDS reorder: dst-sorted edge list
    for (int i = tid; i < n; i += 512) {
        int pkv = bp[i];
        int dl = pkv >> 18;
        int p = atomicAdd(&cur[dl], 1);
        sorted[p] = pkv & 0x3FFFF;
        rowid[p]  = (unsigned short)dl;
    }
    __syncthreads();

    // monotone coalesced write-out of padded rows
    for (int i = tid; i < n; i += 512) {
        int dl = rowid[i];
        int slot = i - off[dl];
        if (slot < CAP)
            buf[(size_t)(b * PSZ_F + dl) * CAP + slot] = sorted[i];
    }
}

// ---------- layer 1: zn[v] = (i0, i1, dv, 0) -- f32 partial accumulators ----------
__global__ void __launch_bounds__(256) k_l1a(const int* __restrict__ cnt,
                                             const int* __restrict__ buf,
                                             const float4* __restrict__ xdc,
                                             float4* __restrict__ zn) {
    int v = blockIdx.x * 256 + threadIdx.x;
    if (v >= N_NODES) return;
    int c = cnt[v];
    int n = (c < CAP) ? c : CAP;
    const int* __restrict__ rowp = buf + v * CAP;
    float4 self = xdc[v];
    float dv = self.z;
    float ax = self.x, ay = self.y;
    float bx = 0.0f,   by = 0.0f;
    int j = 0;
    for (; j + 16 <= n; j += 16) {
        v4i r0 = __builtin_nontemporal_load((const v4i*)(rowp + j));
        v4i r1 = __builtin_nontemporal_load((const v4i*)(rowp + j + 4));
        v4i r2 = __builtin_nontemporal_load((const v4i*)(rowp + j + 8));
        v4i r3 = __builtin_nontemporal_load((const v4i*)(rowp + j + 12));
        float4 p0 = xdc[r0.x], p1 = xdc[r0.y], p2 = xdc[r0.z], p3 = xdc[r0.w];
        float4 p4 = xdc[r1.x], p5 = xdc[r1.y], p6 = xdc[r1.z], p7 = xdc[r1.w];
        float4 p8 = xdc[r2.x], p9 = xdc[r2.y], pa = xdc[r2.z], pb = xdc[r2.w];
        float4 pc = xdc[r3.x], pd = xdc[r3.y], pe = xdc[r3.z], pf = xdc[r3.w];
        ax += p0.x; ay += p0.y;  bx += p1.x; by += p1.y;
        ax += p2.x; ay += p2.y;  bx += p3.x; by += p3.y;
        ax += p4.x; ay += p4.y;  bx += p5.x; by += p5.y;
        ax += p6.x; ay += p6.y;  bx += p7.x; by += p7.y;
        ax += p8.x; ay += p8.y;  bx += p9.x; by += p9.y;
        ax += pa.x; ay += pa.y;  bx += pb.x; by += pb.y;
        ax += pc.x; ay += pc.y;  bx += pd.x; by += pd.y;
        ax += pe.x; ay += pe.y;  bx += pf.x; by += pf.y;
    }
    for (; j + 8 <= n; j += 8) {
        v4i r0 = __builtin_nontemporal_load((const v4i*)(rowp + j));
        v4i r1 = __builtin_nontemporal_load((const v4i*)(rowp + j + 4));
        float4 p0 = xdc[r0.x], p1 = xdc[r0.y], p2 = xdc[r0.z], p3 = xdc[r0.w];
        float4 p4 = xdc[r1.x], p5 = xdc[r1.y], p6 = xdc[r1.z], p7 = xdc[r1.w];
        ax += p0.x; ay += p0.y;  bx += p1.x; by += p1.y;
        ax += p2.x; ay += p2.y;  bx += p3.x; by += p3.y;
        ax += p4.x; ay += p4.y;  bx += p5.x; by += p5.y;
        ax += p6.x; ay += p6.y;  bx += p7.x; by += p7.y;
    }
    for (; j < n; ++j) {
        int s = rowp[j];
        float4 p = xdc[s];
        ax += p.x; ay += p.y;
    }
    zn[v] = make_float4((ax + bx) * dv, (ay + by) * dv, dv, 0.0f);
}

// ---------- layer 2 + folded fc, var nodes only -- all-f32, LDS broadcast-reads ----------
// R8 structure with ONE change: lane-broadcasts via same-address ds_read_b128
// (HW broadcast, 4 floats/op) from wave-private LDS buffers, replacing 88
// v_readlane (~10cy each, measured R8/R9 pair) with 34 LDS ops. Wave-private
// rows -> same-wave LDS ordering handles RAW, ZERO barriers. FP op order
// bit-identical to R8.
__global__ void __launch_bounds__(256, 4) k_l2(const int* __restrict__ cnt,
                                               const int* __restrict__ buf,
                                               const float4* __restrict__ zn,
                                               const float* __restrict__ W1,
                                               const float* __restrict__ b1,
                                               const float* __restrict__ Wc,
                                               const float* __restrict__ bc,
                                               float* __restrict__ out) {
    __shared__ __align__(16) float4 pb[4][64];   // per-wave neighbor broadcast buf (4KB)
    __shared__ __align__(16) float  avs[4][64];  // per-wave Av broadcast buf (1KB)
    int w = threadIdx.x >> 6, l = threadIdx.x & 63;
    float4* __restrict__ pbw = &pb[w][0];
    float*  __restrict__ avw = &avs[w][0];
    float wc[64];
    #pragma unroll
    for (int jv = 0; jv < 64; ++jv)
        wc[jv] = Wc[jv * 64 + l];
    float w1a = W1[l], w1b = W1[64 + l], bb = b1[l];
    float bcl = bc[l];
    int v0 = blockIdx.x * 16 + w;          // wave w owns v0, v0+4, v0+8, v0+12
    int cc0 = __builtin_amdgcn_readfirstlane(cnt[v0]);
    int cc1 = __builtin_amdgcn_readfirstlane(cnt[v0 + 4]);
    int cc2 = __builtin_amdgcn_readfirstlane(cnt[v0 + 8]);
    int cc3 = __builtin_amdgcn_readfirstlane(cnt[v0 + 12]);

    // hoisted loads: rows + neighbor gathers + selfs, all in flight up front
    int nn[4];
    float4 p[4], zs[4];
    #pragma unroll
    for (int it = 0; it < 4; ++it) {
        int v = v0 + it * 4;
        int c = (it == 0) ? cc0 : (it == 1) ? cc1 : (it == 2) ? cc2 : cc3;
        int n = (c < CAP) ? c : CAP;
        nn[it] = n;
        int ridx = __builtin_nontemporal_load(buf + v * CAP + l);
        int idx  = (l < n) ? ridx : v;
        p[it]  = zn[idx];                  // per-lane gather: lane i = neighbor i
        zs[it] = zn[v];                    // self (uniform)
    }

    #pragma unroll
    for (int it = 0; it < 4; ++it) {
        int v = v0 + it * 4;
        int c = (it == 0) ? cc0 : (it == 1) ? cc1 : (it == 2) ? cc2 : cc3;
        int n = nn[it];
        float dv = rsqrtf((float)c + 1.0f);
        float4 zss = zs[it];

        pbw[l] = p[it];                    // stage this node's neighbors (wave-private)

        float acc0 = fmaxf(fmaf(zss.x, w1a, fmaf(zss.y, w1b, bb)), 0.0f) * zss.z;
        float acc1 = 0.0f;
        int j = 0;
        for (; j + 8 <= n; j += 8) {
            float4 q0 = pbw[j+0], q1 = pbw[j+1], q2 = pbw[j+2], q3 = pbw[j+3];
            float4 q4 = pbw[j+4], q5 = pbw[j+5], q6 = pbw[j+6], q7 = pbw[j+7];
            float h0 = fmaxf(fmaf(q0.x, w1a, fmaf(q0.y, w1b, bb)), 0.0f) * q0.z;
            float h1 = fmaxf(fmaf(q1.x, w1a, fmaf(q1.y, w1b, bb)), 0.0f) * q1.z;
            float h2 = fmaxf(fmaf(q2.x, w1a, fmaf(q2.y, w1b, bb)), 0.0f) * q2.z;
            float h3 = fmaxf(fmaf(q3.x, w1a, fmaf(q3.y, w1b, bb)), 0.0f) * q3.z;
            float h4 = fmaxf(fmaf(q4.x, w1a, fmaf(q4.y, w1b, bb)), 0.0f) * q4.z;
            float h5 = fmaxf(fmaf(q5.x, w1a, fmaf(q5.y, w1b, bb)), 0.0f) * q5.z;
            float h6 = fmaxf(fmaf(q6.x, w1a, fmaf(q6.y, w1b, bb)), 0.0f) * q6.z;
            float h7 = fmaxf(fmaf(q7.x, w1a, fmaf(q7.y, w1b, bb)), 0.0f) * q7.z;
            acc0 += (h0 + h1) + (h2 + h3);
            acc1 += (h4 + h5) + (h6 + h7);
        }
        for (; j + 4 <= n; j += 4) {
            float4 q0 = pbw[j+0], q1 = pbw[j+1], q2 = pbw[j+2], q3 = pbw[j+3];
            float h0 = fmaxf(fmaf(q0.x, w1a, fmaf(q0.y, w1b, bb)), 0.0f) * q0.z;
            float h1 = fmaxf(fmaf(q1.x, w1a, fmaf(q1.y, w1b, bb)), 0.0f) * q1.z;
            float h2 = fmaxf(fmaf(q2.x, w1a, fmaf(q2.y, w1b, bb)), 0.0f) * q2.z;
            float h3 = fmaxf(fmaf(q3.x, w1a, fmaf(q3.y, w1b, bb)), 0.0f) * q3.z;
            acc0 += (h0 + h1) + (h2 + h3);
        }
        for (; j < n; ++j) {
            float4 q0 = pbw[j];
            acc1 += fmaxf(fmaf(q0.x, w1a, fmaf(q0.y, w1b, bb)), 0.0f) * q0.z;
        }
        float Av = (acc0 + acc1) * dv;     // lane l holds channel l's aggregate

        avw[l] = Av;                       // stage Av (wave-private)

        // FC: identical accumulation grouping to R3-R8 -> same FP result.
        float t0 = 0.0f, t1 = 0.0f, t2 = 0.0f, t3 = 0.0f;
        #pragma unroll
        for (int jj = 0; jj < 64; jj += 4) {
            float4 a4 = *(const float4*)&avw[jj];      // same-addr ds_read_b128
            t0 = fmaf(a4.x, wc[jj + 0], t0);
            t1 = fmaf(a4.y, wc[jj + 1], t1);
            t2 = fmaf(a4.z, wc[jj + 2], t2);
            t3 = fmaf(a4.w, wc[jj + 3], t3);
        }
        float t = ((t0 + t1) + (t2 + t3)) + bcl;
        __builtin_nontemporal_store(rintf(fmaxf(t, 0.0f)), out + v * 64 + l);
    }
}

// ---------------- launch ----------------

extern "C" void kernel_launch(void* const* d_in, const int* in_sizes, int n_in,
                              void* d_out, int out_size, void* d_ws, size_t ws_size,
                              hipStream_t stream) {
    const float* x    = (const float*)d_in[0];
    const int*   ei   = (const int*)  d_in[1];
    const float* W1   = (const float*)d_in[2];
    const float* b1   = (const float*)d_in[3];
    const float* W2   = (const float*)d_in[4];
    const float* b2   = (const float*)d_in[5];
    const float* Wfc  = (const float*)d_in[6];
    const float* bfc  = (const float*)d_in[7];
    float* out = (float*)d_out;

    const int* src = ei;
    const int* dst = ei + N_EDGES;

    // workspace layout (bytes), 16-aligned; total 70,420,736 (unchanged size)
    //   cnt  [0, 800000)            written k_sort, read l1a/l2
    //   xdc  [800000, 4000000)      written k_sort, read l1a       (no alias)
    //   bins [4000000, 18680064)    written k_bin, read k_sort
    //   bcnt [18680064, 18682112)   memset, k_bin atomics, k_sort read
    //   zn   [15204096, 18404096)   written l1a (bins dead), read l2
    //   buf  [19204096, 70404096)   written k_sort, read l1a/l2
    //   Wc/bc[70404096, 70420736)   written k_bin blocks 0..8, read l2
    char* ws = (char*)d_ws;
    int*    cnt    = (int*)   (ws + 0);
    float4* xdc    = (float4*)(ws + 800000);
    int*    bins   = (int*)   (ws + 4000000);
    int*    bcnt   = (int*)   (ws + 18680064);
    float4* zn     = (float4*)(ws + 15204096);   // aliases dead bins tail
    int*    buf    = (int*)   (ws + 19204096);
    float*  Wc     = (float*) (ws + 70404096);
    float*  bc     = (float*) (ws + 70420480);

    hipMemsetAsync(bcnt, 0, NFINE * sizeof(int), stream);
    k_bin  <<<NB_BIN, 512, 0, stream>>>(src, dst, bins, bcnt, W2, b2, Wfc, bfc, Wc, bc);
    k_sort <<<NFINE, 512, 0, stream>>>(bins, bcnt, (const float2*)x, cnt, xdc, buf);
    k_l1a  <<<NB_SCAN, 256, 0, stream>>>(cnt, buf, xdc, zn);
    k_l2   <<<N_VAR / 16, 256, 0, stream>>>(cnt, buf, zn, W1, b1, Wc, bc, out);
}

// Round 11
// 198.837 us; speedup vs baseline: 1.1038x; 1.0363x over previous
//
#include <hip/hip_runtime.h>
#include <math.h>

#define N_NODES 200000
#define N_VAR   112000
#define N_EDGES 3200000
#define CAP     64            // padded row capacity (P(deg>=64)~1e-24); == wave size

// ---- two-level counting-sort params ----
#define NFINE    512          // fine dst-range buckets
#define PSZ_F    391          // nodes per bucket (512*391 = 200192 >= 200000)
#define FCAP     7168         // per-bucket edge capacity (mean 6250, ~11.6 sigma slack)
#define BIN_CHUNK 8192        // edges per k_bin block (391 blocks; measured best)
#define NB_BIN   391          // ceil(3.2e6/8192)
#define NB_L1    12500        // 200000 / 16 nodes per block

typedef int v4i __attribute__((ext_vector_type(4)));

// ---------- phase A: bin edges into 512 dst-range buckets + folded setup ----------
// Packed entry: (dst_local<<18 | src), dst_local<391 (9b), src<2^18.
// 8192-edge chunks + wave-shuffle scan (2 barriers) + fused Wc/bc fold.
__global__ void __launch_bounds__(512) k_bin(const int* __restrict__ src,
                                             const int* __restrict__ dst,
                                             int* __restrict__ bins,
                                             int* __restrict__ bcnt,
                                             const float* __restrict__ W2,
                                             const float* __restrict__ b2,
                                             const float* __restrict__ Wfc,
                                             const float* __restrict__ bfc,
                                             float* __restrict__ Wc,
                                             float* __restrict__ bc) {
    __shared__ int hist[NFINE];
    __shared__ int seg[NFINE];
    __shared__ int gb[NFINE];
    __shared__ int cur[NFINE];
    __shared__ int wsum[8];
    __shared__ int stg[BIN_CHUNK];
    __shared__ unsigned short stgb[BIN_CHUNK];
    int tid = threadIdx.x;
    int lane = tid & 63, wid = tid >> 6;
    hist[tid] = 0;
    __syncthreads();

    int base = blockIdx.x * BIN_CHUNK;
    int pk[4][4];
    int bk[4][4];
    bool val[4];
    #pragma unroll
    for (int i = 0; i < 4; ++i) {
        int e4 = base + (i * 512 + tid) * 4;
        val[i] = (e4 < N_EDGES);       // N_EDGES % 4 == 0 -> full quad if valid
        if (val[i]) {
            v4i d = __builtin_nontemporal_load((const v4i*)(dst + e4));
            v4i s = __builtin_nontemporal_load((const v4i*)(src + e4));
            int dd[4] = {d.x, d.y, d.z, d.w};
            int ss[4] = {s.x, s.y, s.z, s.w};
            #pragma unroll
            for (int q = 0; q < 4; ++q) {
                int bb2 = dd[q] / PSZ_F;               // const div -> magic mul
                int dl = dd[q] - bb2 * PSZ_F;          // < 391 (9 bits)
                pk[i][q] = (dl << 18) | ss[q];
                bk[i][q] = bb2;
                atomicAdd(&hist[bb2], 1);
            }
        }
    }
    __syncthreads();

    // wave-shuffle inclusive scan over 512 entries (2 barriers total)
    int h = hist[tid];
    int inc = h;
    #pragma unroll
    for (int d = 1; d < 64; d <<= 1) {
        int t = __shfl_up(inc, d);
        if (lane >= d) inc += t;
    }
    if (lane == 63) wsum[wid] = inc;
    __syncthreads();
    int pre = 0, tot = 0;
    #pragma unroll
    for (int k = 0; k < 8; ++k) {
        int s = wsum[k];
        pre += (k < wid) ? s : 0;
        tot += s;
    }
    int ex = pre + inc - h;
    seg[tid] = ex;
    cur[tid] = ex;
    gb[tid]  = atomicAdd(&bcnt[tid], h);
    __syncthreads();

    // compact into stg by bucket
    #pragma unroll
    for (int i = 0; i < 4; ++i) {
        if (val[i]) {
            #pragma unroll
            for (int q = 0; q < 4; ++q) {
                int p = atomicAdd(&cur[bk[i][q]], 1);
                stg[p]  = pk[i][q];
                stgb[p] = (unsigned short)bk[i][q];
            }
        }
    }
    __syncthreads();

    // coalesced copy-out: per-bucket contiguous runs (avg 16 edges = 64B)
    for (int i = tid; i < tot; i += 512) {
        int bb2 = stgb[i];
        int pos = gb[bb2] + (i - seg[bb2]);
        if (pos < FCAP)
            bins[(size_t)bb2 * FCAP + pos] = stg[i];
    }

    // folded setup (identical f64 math to original k_setup)
    int b = blockIdx.x;
    if (b < 8) {
        int e = b * 512 + tid;             // 4096 entries
        int j = e >> 6, l2 = e & 63;
        double acc = 0.0;
        for (int m = 0; m < 64; ++m)
            acc += (double)W2[j * 64 + m] * (double)Wfc[m * 64 + l2];
        Wc[e] = (float)acc;
    } else if (b == 8 && tid < 64) {
        double acc = (double)bfc[tid];
        for (int m = 0; m < 64; ++m)
            acc += (double)b2[m] * (double)Wfc[m * 64 + tid];
        bc[tid] = (float)acc;
    }
}

// ---------- phase B: per-bucket counting sort -> exact cnt + xdc + coalesced buf ----------
__global__ void __launch_bounds__(512) k_sort(const int* __restrict__ bins,
                                              const int* __restrict__ bcnt,
                                              const float2* __restrict__ x2,
                                              int* __restrict__ cnt,
                                              float4* __restrict__ xdc,
                                              int* __restrict__ buf) {
    __shared__ int hist[NFINE];
    __shared__ int off[NFINE];
    __shared__ int cur[NFINE];
    __shared__ int wsum[8];
    __shared__ int sorted[FCAP];
    __shared__ unsigned short rowid[FCAP];
    int tid = threadIdx.x;
    int lane = tid & 63, wid = tid >> 6;
    int b = blockIdx.x;
    int n = bcnt[b];
    if (n > FCAP) n = FCAP;
    const int* __restrict__ bp = bins + (size_t)b * FCAP;

    hist[tid] = 0;
    __syncthreads();
    for (int i = tid; i < n; i += 512)
        atomicAdd(&hist[bp[i] >> 18], 1);
    __syncthreads();

    int h = hist[tid];

    // exact degree -> cnt + xdc (fused k_post; same math)
    int vg = b * PSZ_F + tid;
    if (tid < PSZ_F && vg < N_NODES) {
        cnt[vg] = h;
        float dvv = rsqrtf((float)h + 1.0f);
        float2 xv = x2[vg];
        xdc[vg] = make_float4(xv.x * dvv, xv.y * dvv, dvv, 0.0f);
    }

    // wave-shuffle inclusive scan -> exclusive offsets
    int inc = h;
    #pragma unroll
    for (int d = 1; d < 64; d <<= 1) {
        int t = __shfl_up(inc, d);
        if (lane >= d) inc += t;
    }
    if (lane == 63) wsum[wid] = inc;
    __syncthreads();
    int pre = 0;
    #pragma unroll
    for (int k = 0; k < 8; ++k) {
        int s = wsum[k];
        pre += (k < wid) ? s : 0;
    }
    int ex = pre + inc - h;
    off[tid] = ex;
    cur[tid] = ex;
    __syncthreads();

    // LDS reorder: dst-sorted edge list
    for (int i = tid; i < n; i += 512) {
        int pkv = bp[i];
        int dl = pkv >> 18;
        int p = atomicAdd(&cur[dl], 1);
        sorted[p] = pkv & 0x3FFFF;
        rowid[p]  = (unsigned short)dl;
    }
    __syncthreads();

    // monotone coalesced write-out of padded rows
    for (int i = tid; i < n; i += 512) {
        int dl = rowid[i];
        int slot = i - off[dl];
        if (slot < CAP)
            buf[(size_t)(b * PSZ_F + dl) * CAP + slot] = sorted[i];
    }
}

// ---------- layer 1 -- RESTRUCTURED: k_l2-style wave-per-4-nodes ----------
// Old: one thread per node, ragged serial gather chain (wave serializes to
// max-deg-in-wave ~30, scalar tails pay full rowload->gather latency each).
// New: per node ONE row load + ONE per-lane float2 gather (all neighbor lines
// in flight in a single instr), LDS stage, wave-uniform same-address
// broadcast-read sum. Add sequence replicates the old loop EXACTLY
// (q=(p0.x,p0.y,p1.x,p1.y) -> ax,ay,bx,by in original order) -> bit-identical.
__global__ void __launch_bounds__(256, 4) k_l1a(const int* __restrict__ cnt,
                                                const int* __restrict__ buf,
                                                const float4* __restrict__ xdc,
                                                float4* __restrict__ zn) {
    __shared__ __align__(16) float2 pb2[4][64];   // per-wave stage (2KB)
    int w = threadIdx.x >> 6, l = threadIdx.x & 63;
    float2* __restrict__ pbw = &pb2[w][0];
    int v0 = blockIdx.x * 16 + w;          // wave w owns v0, v0+4, v0+8, v0+12
    int cc0 = __builtin_amdgcn_readfirstlane(cnt[v0]);
    int cc1 = __builtin_amdgcn_readfirstlane(cnt[v0 + 4]);
    int cc2 = __builtin_amdgcn_readfirstlane(cnt[v0 + 8]);
    int cc3 = __builtin_amdgcn_readfirstlane(cnt[v0 + 12]);

    // hoisted loads: rows + per-lane gathers + selfs, all in flight up front
    int nn[4];
    float2 g[4];
    float4 zs[4];
    #pragma unroll
    for (int it = 0; it < 4; ++it) {
        int v = v0 + it * 4;
        int c = (it == 0) ? cc0 : (it == 1) ? cc1 : (it == 2) ? cc2 : cc3;
        int n = (c < CAP) ? c : CAP;
        nn[it] = n;
        int ridx = __builtin_nontemporal_load(buf + v * CAP + l);
        int idx  = (l < n) ? ridx : v;
        g[it]  = *(const float2*)&xdc[idx];   // (x*dv, y*dv), 8B
        zs[it] = xdc[v];                      // self incl. dv (uniform)
    }

    #pragma unroll
    for (int it = 0; it < 4; ++it) {
        int v = v0 + it * 4;
        int n = nn[it];
        float4 self = zs[it];
        float dv = self.z;
        pbw[l] = g[it];                    // wave-private stage, no barrier

        float ax = self.x, ay = self.y;
        float bx = 0.0f,   by = 0.0f;
        int j = 0;
        for (; j + 16 <= n; j += 16) {
            float4 q0 = *(const float4*)&pbw[j +  0];   // (p0.x p0.y p1.x p1.y)
            float4 q1 = *(const float4*)&pbw[j +  2];
            float4 q2 = *(const float4*)&pbw[j +  4];
            float4 q3 = *(const float4*)&pbw[j +  6];
            float4 q4 = *(const float4*)&pbw[j +  8];
            float4 q5 = *(const float4*)&pbw[j + 10];
            float4 q6 = *(const float4*)&pbw[j + 12];
            float4 q7 = *(const float4*)&pbw[j + 14];
            ax += q0.x; ay += q0.y;  bx += q0.z; by += q0.w;
            ax += q1.x; ay += q1.y;  bx += q1.z; by += q1.w;
            ax += q2.x; ay += q2.y;  bx += q2.z; by += q2.w;
            ax += q3.x; ay += q3.y;  bx += q3.z; by += q3.w;
            ax += q4.x; ay += q4.y;  bx += q4.z; by += q4.w;
            ax += q5.x; ay += q5.y;  bx += q5.z; by += q5.w;
            ax += q6.x; ay += q6.y;  bx += q6.z; by += q6.w;
            ax += q7.x; ay += q7.y;  bx += q7.z; by += q7.w;
        }
        for (; j + 8 <= n; j += 8) {
            float4 q0 = *(const float4*)&pbw[j + 0];
            float4 q1 = *(const float4*)&pbw[j + 2];
            float4 q2 = *(const float4*)&pbw[j + 4];
            float4 q3 = *(const float4*)&pbw[j + 6];
            ax += q0.x; ay += q0.y;  bx += q0.z; by += q0.w;
            ax += q1.x; ay += q1.y;  bx += q1.z; by += q1.w;
            ax += q2.x; ay += q2.y;  bx += q2.z; by += q2.w;
            ax += q3.x; ay += q3.y;  bx += q3.z; by += q3.w;
        }
        for (; j < n; ++j) {
            float2 q = pbw[j];
            ax += q.x; ay += q.y;
        }
        if (l == 0)
            zn[v] = make_float4((ax + bx) * dv, (ay + by) * dv, dv, 0.0f);
    }
}

// ---------- layer 2 + folded fc -- R10 verbatim (measured 59us) ----------
__global__ void __launch_bounds__(256, 4) k_l2(const int* __restrict__ cnt,
                                               const int* __restrict__ buf,
                                               const float4* __restrict__ zn,
                                               const float* __restrict__ W1,
                                               const float* __restrict__ b1,
                                               const float* __restrict__ Wc,
                                               const float* __restrict__ bc,
                                               float* __restrict__ out) {
    __shared__ __align__(16) float4 pb[4][64];   // per-wave neighbor broadcast buf (4KB)
    __shared__ __align__(16) float  avs[4][64];  // per-wave Av broadcast buf (1KB)
    int w = threadIdx.x >> 6, l = threadIdx.x & 63;
    float4* __restrict__ pbw = &pb[w][0];
    float*  __restrict__ avw = &avs[w][0];
    float wc[64];
    #pragma unroll
    for (int jv = 0; jv < 64; ++jv)
        wc[jv] = Wc[jv * 64 + l];
    float w1a = W1[l], w1b = W1[64 + l], bb = b1[l];
    float bcl = bc[l];
    int v0 = blockIdx.x * 16 + w;          // wave w owns v0, v0+4, v0+8, v0+12
    int cc0 = __builtin_amdgcn_readfirstlane(cnt[v0]);
    int cc1 = __builtin_amdgcn_readfirstlane(cnt[v0 + 4]);
    int cc2 = __builtin_amdgcn_readfirstlane(cnt[v0 + 8]);
    int cc3 = __builtin_amdgcn_readfirstlane(cnt[v0 + 12]);

    // hoisted loads: rows + neighbor gathers + selfs, all in flight up front
    int nn[4];
    float4 p[4], zs[4];
    #pragma unroll
    for (int it = 0; it < 4; ++it) {
        int v = v0 + it * 4;
        int c = (it == 0) ? cc0 : (it == 1) ? cc1 : (it == 2) ? cc2 : cc3;
        int n = (c < CAP) ? c : CAP;
        nn[it] = n;
        int ridx = __builtin_nontemporal_load(buf + v * CAP + l);
        int idx  = (l < n) ? ridx : v;
        p[it]  = zn[idx];                  // per-lane gather: lane i = neighbor i
        zs[it] = zn[v];                    // self (uniform)
    }

    #pragma unroll
    for (int it = 0; it < 4; ++it) {
        int v = v0 + it * 4;
        int c = (it == 0) ? cc0 : (it == 1) ? cc1 : (it == 2) ? cc2 : cc3;
        int n = nn[it];
        float dv = rsqrtf((float)c + 1.0f);
        float4 zss = zs[it];

        pbw[l] = p[it];                    // stage this node's neighbors (wave-private)

        float acc0 = fmaxf(fmaf(zss.x, w1a, fmaf(zss.y, w1b, bb)), 0.0f) * zss.z;
        float acc1 = 0.0f;
        int j = 0;
        for (; j + 8 <= n; j += 8) {
            float4 q0 = pbw[j+0], q1 = pbw[j+1], q2 = pbw[j+2], q3 = pbw[j+3];
            float4 q4 = pbw[j+4], q5 = pbw[j+5], q6 = pbw[j+6], q7 = pbw[j+7];
            float h0 = fmaxf(fmaf(q0.x, w1a, fmaf(q0.y, w1b, bb)), 0.0f) * q0.z;
            float h1 = fmaxf(fmaf(q1.x, w1a, fmaf(q1.y, w1b, bb)), 0.0f) * q1.z;
            float h2 = fmaxf(fmaf(q2.x, w1a, fmaf(q2.y, w1b, bb)), 0.0f) * q2.z;
            float h3 = fmaxf(fmaf(q3.x, w1a, fmaf(q3.y, w1b, bb)), 0.0f) * q3.z;
            float h4 = fmaxf(fmaf(q4.x, w1a, fmaf(q4.y, w1b, bb)), 0.0f) * q4.z;
            float h5 = fmaxf(fmaf(q5.x, w1a, fmaf(q5.y, w1b, bb)), 0.0f) * q5.z;
            float h6 = fmaxf(fmaf(q6.x, w1a, fmaf(q6.y, w1b, bb)), 0.0f) * q6.z;
            float h7 = fmaxf(fmaf(q7.x, w1a, fmaf(q7.y, w1b, bb)), 0.0f) * q7.z;
            acc0 += (h0 + h1) + (h2 + h3);
            acc1 += (h4 + h5) + (h6 + h7);
        }
        for (; j + 4 <= n; j += 4) {
            float4 q0 = pbw[j+0], q1 = pbw[j+1], q2 = pbw[j+2], q3 = pbw[j+3];
            float h0 = fmaxf(fmaf(q0.x, w1a, fmaf(q0.y, w1b, bb)), 0.0f) * q0.z;
            float h1 = fmaxf(fmaf(q1.x, w1a, fmaf(q1.y, w1b, bb)), 0.0f) * q1.z;
            float h2 = fmaxf(fmaf(q2.x, w1a, fmaf(q2.y, w1b, bb)), 0.0f) * q2.z;
            float h3 = fmaxf(fmaf(q3.x, w1a, fmaf(q3.y, w1b, bb)), 0.0f) * q3.z;
            acc0 += (h0 + h1) + (h2 + h3);
        }
        for (; j < n; ++j) {
            float4 q0 = pbw[j];
            acc1 += fmaxf(fmaf(q0.x, w1a, fmaf(q0.y, w1b, bb)), 0.0f) * q0.z;
        }
        float Av = (acc0 + acc1) * dv;     // lane l holds channel l's aggregate

        avw[l] = Av;                       // stage Av (wave-private)

        // FC: identical accumulation grouping to R3-R10 -> same FP result.
        float t0 = 0.0f, t1 = 0.0f, t2 = 0.0f, t3 = 0.0f;
        #pragma unroll
        for (int jj = 0; jj < 64; jj += 4) {
            float4 a4 = *(const float4*)&avw[jj];      // same-addr ds_read_b128
            t0 = fmaf(a4.x, wc[jj + 0], t0);
            t1 = fmaf(a4.y, wc[jj + 1], t1);
            t2 = fmaf(a4.z, wc[jj + 2], t2);
            t3 = fmaf(a4.w, wc[jj + 3], t3);
        }
        float t = ((t0 + t1) + (t2 + t3)) + bcl;
        __builtin_nontemporal_store(rintf(fmaxf(t, 0.0f)), out + v * 64 + l);
    }
}

// ---------------- launch ----------------

extern "C" void kernel_launch(void* const* d_in, const int* in_sizes, int n_in,
                              void* d_out, int out_size, void* d_ws, size_t ws_size,
                              hipStream_t stream) {
    const float* x    = (const float*)d_in[0];
    const int*   ei   = (const int*)  d_in[1];
    const float* W1   = (const float*)d_in[2];
    const float* b1   = (const float*)d_in[3];
    const float* W2   = (const float*)d_in[4];
    const float* b2   = (const float*)d_in[5];
    const float* Wfc  = (const float*)d_in[6];
    const float* bfc  = (const float*)d_in[7];
    float* out = (float*)d_out;

    const int* src = ei;
    const int* dst = ei + N_EDGES;

    // workspace layout (bytes), 16-aligned; total 70,420,736 (unchanged size)
    //   cnt  [0, 800000)            written k_sort, read l1a/l2
    //   xdc  [800000, 4000000)      written k_sort, read l1a       (no alias)
    //   bins [4000000, 18680064)    written k_bin, read k_sort
    //   bcnt [18680064, 18682112)   memset, k_bin atomics, k_sort read
    //   zn   [15204096, 18404096)   written l1a (bins dead), read l2
    //   buf  [19204096, 70404096)   written k_sort, read l1a/l2
    //   Wc/bc[70404096, 70420736)   written k_bin blocks 0..8, read l2
    char* ws = (char*)d_ws;
    int*    cnt    = (int*)   (ws + 0);
    float4* xdc    = (float4*)(ws + 800000);
    int*    bins   = (int*)   (ws + 4000000);
    int*    bcnt   = (int*)   (ws + 18680064);
    float4* zn     = (float4*)(ws + 15204096);   // aliases dead bins tail
    int*    buf    = (int*)   (ws + 19204096);
    float*  Wc     = (float*) (ws + 70404096);
    float*  bc     = (float*) (ws + 70420480);

    hipMemsetAsync(bcnt, 0, NFINE * sizeof(int), stream);
    k_bin  <<<NB_BIN, 512, 0, stream>>>(src, dst, bins, bcnt, W2, b2, Wfc, bfc, Wc, bc);
    k_sort <<<NFINE, 512, 0, stream>>>(bins, bcnt, (const float2*)x, cnt, xdc, buf);
    k_l1a  <<<NB_L1, 256, 0, stream>>>(cnt, buf, xdc, zn);
    k_l2   <<<N_VAR / 16, 256, 0, stream>>>(cnt, buf, zn, W1, b1, Wc, bc, out);
}